// Round 6
// baseline (3420.305 us; speedup 1.0000x reference)
//
#include <hip/hip_runtime.h>
#include <math.h>

#define BATCH 128
#define SLEN  8000
#define HID   64
#define CHUNK 64                  // steps per fc flush; 8000 = 125 * 64
#define NCHUNK (SLEN / CHUNK)     // 125
#define ROWSTRIDE 68              // floats; even -> float2-aligned, conflict-free

__device__ __forceinline__ float fast_exp2(float x) { return __builtin_amdgcn_exp2f(x); }
__device__ __forceinline__ float fast_rcp(float x)  { return __builtin_amdgcn_rcpf(x); }

__device__ __forceinline__ float bcast_lane(float v, int lane) {
    return __int_as_float(__builtin_amdgcn_readlane(__float_as_int(v), lane));
}

// tanh(x) = sign(x) * (e - 1)/(e + 1), e = 2^(2|x|*log2 e)   (UNCHANGED - bitwise)
__device__ __forceinline__ float tanh_fast(float x) {
    float ax = fabsf(x);
    float z  = fminf(ax * 2.8853900817779268f, 30.0f);
    float e  = fast_exp2(z);
    float r  = (e - 1.0f) * fast_rcp(e + 1.0f);
    return x < 0.0f ? -r : r;
}

__device__ __forceinline__ float sigmoid_fast(float x) {
    float z = fminf(fmaxf(-x * 1.4426950408889634f, -60.0f), 60.0f);
    float e = fast_exp2(z);
    return fast_rcp(1.0f + e);
}

// Two independent recurrences per wave. A solo wave issues ~1 instr / 4 cyc and
// has ~190 cyc/step of unfillable latency (LDS turnaround + tanh chain); a
// second sequence's instruction stream fills both. Weights shared; per-stream
// math identical to the single-seq kernel -> bitwise-identical outputs.
// Stream A uses SGPR scratch s[60:61], stream B uses s[62:63].
#define PK_RLA(J0, J1, ACC, WPK)                                            \
    asm volatile("v_readlane_b32 s60, %1, " #J0 "\n\t"                      \
                 "v_readlane_b32 s61, %1, " #J1 "\n\t"                      \
                 "v_pk_fma_f32 %0, %2, s[60:61], %0"                        \
                 : "+v"(ACC) : "v"(hA), "v"(WPK) : "s60", "s61")

#define PK_RLB(J0, J1, ACC, WPK)                                            \
    asm volatile("v_readlane_b32 s62, %1, " #J0 "\n\t"                      \
                 "v_readlane_b32 s63, %1, " #J1 "\n\t"                      \
                 "v_pk_fma_f32 %0, %2, s[62:63], %0"                        \
                 : "+v"(ACC) : "v"(hB), "v"(WPK) : "s62", "s63")

#define PK_V(ACC, WPK, HPK)                                                 \
    asm volatile("v_pk_fma_f32 %0, %1, %2, %0"                              \
                 : "+v"(ACC) : "v"(WPK), "v"(HPK))

__global__ __launch_bounds__(64) void rnn_dual_kernel(
    const float* __restrict__ x,      // [B, S]
    const float* __restrict__ W_ih,   // [H, 1]
    const float* __restrict__ b_ih,   // [H]
    const float* __restrict__ W_hh,   // [H, H]
    const float* __restrict__ b_hh,   // [H]
    const float* __restrict__ fc_w,   // [2, H]
    const float* __restrict__ fc_b,   // [2]
    float* __restrict__ out)          // [B]
{
    __shared__ float hbA[CHUNK * ROWSTRIDE];
    __shared__ float hbB[CHUNK * ROWSTRIDE];

    const int lane = threadIdx.x;               // == hidden index i
    const int b    = blockIdx.x;                // handles seqs 2b, 2b+1
    const float* xrowA = x + (size_t)(2 * b) * SLEN;
    const float* xrowB = x + (size_t)(2 * b + 1) * SLEN;

    // Lane i holds W_hh row i, packed as float2 pairs (SHARED by both streams):
    //  wpk[2q]   = (w[4q],   w[4q+1])  -> a01 chain pair   (j < 32)
    //  wpk[2q+1] = (w[4q+2], w[4q+3])  -> a23 chain pair
    //  wpkh      = same for j >= 32
    float2 wpk[16], wpkh[16];
    #pragma unroll
    for (int q = 0; q < 8; ++q) {
        float4 t = ((const float4*)(W_hh + lane * HID))[q];
        wpk[2*q]   = make_float2(t.x, t.y);
        wpk[2*q+1] = make_float2(t.z, t.w);
    }
    #pragma unroll
    for (int q = 0; q < 8; ++q) {
        float4 t = ((const float4*)(W_hh + lane * HID))[8 + q];
        wpkh[2*q]   = make_float2(t.x, t.y);
        wpkh[2*q+1] = make_float2(t.z, t.w);
    }
    const float wih  = W_ih[lane];
    const float bias = b_ih[lane] + b_hh[lane];
    const float fcb0 = fc_b[0], fcb1 = fc_b[1];

    float hA = 0.0f, hB = 0.0f;     // lane i holds h[i] of each stream
    float numA = 0.0f, denA = 0.0f;
    float numB = 0.0f, denB = 0.0f;

    // h_{-1} = 0 lives in row 63 (read by step r=0 of chunk 0)
    hbA[63 * ROWSTRIDE + lane] = 0.0f;
    hbB[63 * ROWSTRIDE + lane] = 0.0f;

    float xv_nextA = xrowA[lane];
    float xv_nextB = xrowB[lane];

    #pragma unroll 1
    for (int c = 0; c < NCHUNK; ++c) {
        float xcurA = xv_nextA;
        float xcurB = xv_nextB;
        int nidx = (c + 1 < NCHUNK) ? (c + 1) * CHUNK + lane : lane;
        xv_nextA = xrowA[nidx];
        xv_nextB = xrowB[nidx];

        #pragma unroll 2
        for (int r = 0; r < CHUNK; ++r) {
            // ---- issue both streams' LDS broadcast reads EARLY (prev h rows) ----
            const float2* hpA = (const float2*)(hbA + ((r + 63) & 63) * ROWSTRIDE);
            const float2* hpB = (const float2*)(hbB + ((r + 63) & 63) * ROWSTRIDE);
            float2 hhA[16], hhB[16];
            #pragma unroll
            for (int q = 0; q < 16; ++q) hhA[q] = hpA[16 + q];   // floats 32..63
            #pragma unroll
            for (int q = 0; q < 16; ++q) hhB[q] = hpB[16 + q];

            float xvA = bcast_lane(xcurA, r);
            float xvB = bcast_lane(xcurB, r);

            float2 a01A = make_float2(fmaf(wih, xvA, bias), 0.0f);
            float2 a23A = make_float2(0.0f, 0.0f);
            float2 a01B = make_float2(fmaf(wih, xvB, bias), 0.0f);
            float2 a23B = make_float2(0.0f, 0.0f);

            // ---- j = 0..31 readlane sections, A/B interleaved ----
            PK_RLA( 0,  1, a01A, wpk[0]);  PK_RLB( 0,  1, a01B, wpk[0]);
            PK_RLA( 2,  3, a23A, wpk[1]);  PK_RLB( 2,  3, a23B, wpk[1]);
            PK_RLA( 4,  5, a01A, wpk[2]);  PK_RLB( 4,  5, a01B, wpk[2]);
            PK_RLA( 6,  7, a23A, wpk[3]);  PK_RLB( 6,  7, a23B, wpk[3]);
            PK_RLA( 8,  9, a01A, wpk[4]);  PK_RLB( 8,  9, a01B, wpk[4]);
            PK_RLA(10, 11, a23A, wpk[5]);  PK_RLB(10, 11, a23B, wpk[5]);
            PK_RLA(12, 13, a01A, wpk[6]);  PK_RLB(12, 13, a01B, wpk[6]);
            PK_RLA(14, 15, a23A, wpk[7]);  PK_RLB(14, 15, a23B, wpk[7]);
            PK_RLA(16, 17, a01A, wpk[8]);  PK_RLB(16, 17, a01B, wpk[8]);
            PK_RLA(18, 19, a23A, wpk[9]);  PK_RLB(18, 19, a23B, wpk[9]);
            PK_RLA(20, 21, a01A, wpk[10]); PK_RLB(20, 21, a01B, wpk[10]);
            PK_RLA(22, 23, a23A, wpk[11]); PK_RLB(22, 23, a23B, wpk[11]);
            PK_RLA(24, 25, a01A, wpk[12]); PK_RLB(24, 25, a01B, wpk[12]);
            PK_RLA(26, 27, a23A, wpk[13]); PK_RLB(26, 27, a23B, wpk[13]);
            PK_RLA(28, 29, a01A, wpk[14]); PK_RLB(28, 29, a01B, wpk[14]);
            PK_RLA(30, 31, a23A, wpk[15]); PK_RLB(30, 31, a23B, wpk[15]);

            // ---- j = 32..63 from LDS broadcast pairs ----
            #pragma unroll
            for (int q = 0; q < 8; ++q) {
                PK_V(a01A, wpkh[2*q],   hhA[2*q]);
                PK_V(a23A, wpkh[2*q+1], hhA[2*q+1]);
            }
            #pragma unroll
            for (int q = 0; q < 8; ++q) {
                PK_V(a01B, wpkh[2*q],   hhB[2*q]);
                PK_V(a23B, wpkh[2*q+1], hhB[2*q+1]);
            }

            // ---- finish A, then B (B's work hides A's tanh latency) ----
            float aA = (a01A.x + a01A.y) + (a23A.x + a23A.y);
            hA = tanh_fast(aA);
            hbA[r * ROWSTRIDE + lane] = hA;

            float aB = (a01B.x + a01B.y) + (a23B.x + a23B.y);
            hB = tanh_fast(aB);
            hbB[r * ROWSTRIDE + lane] = hB;
        }
        __syncthreads();   // single wave -> lgkmcnt drain only

        // ---- fc heads: lane processes row `lane` for each stream ----
        {
            const float4* rpA = (const float4*)(hbA + lane * ROWSTRIDE);
            const float4* rpB = (const float4*)(hbB + lane * ROWSTRIDE);
            float d0A = 0.f, d1A = 0.f, d0B = 0.f, d1B = 0.f;
            #pragma unroll
            for (int q = 0; q < 16; ++q) {
                float4 hvA = rpA[q];
                float4 hvB = rpB[q];
                float4 f0 = ((const float4*)fc_w)[q];          // uniform -> s_load
                float4 f1 = ((const float4*)(fc_w + HID))[q];
                d0A += hvA.x * f0.x + hvA.y * f0.y + hvA.z * f0.z + hvA.w * f0.w;
                d1A += hvA.x * f1.x + hvA.y * f1.y + hvA.z * f1.z + hvA.w * f1.w;
                d0B += hvB.x * f0.x + hvB.y * f0.y + hvB.z * f0.z + hvB.w * f0.w;
                d1B += hvB.x * f1.x + hvB.y * f1.y + hvB.z * f1.z + hvB.w * f1.w;
            }
            float selA = sigmoid_fast(d0A + fcb0);
            float scoA = sigmoid_fast(d1A + fcb1);
            numA = fmaf(scoA, selA, numA);
            denA += selA;
            float selB = sigmoid_fast(d0B + fcb0);
            float scoB = sigmoid_fast(d1B + fcb1);
            numB = fmaf(scoB, selB, numB);
            denB += selB;
        }
        __syncthreads();   // hbuf reads done before next chunk overwrites
    }

    // Final cross-lane reductions (one tree per stream, same shape as before)
    #pragma unroll
    for (int off = 32; off > 0; off >>= 1) {
        numA += __shfl_down(numA, off);
        denA += __shfl_down(denA, off);
        numB += __shfl_down(numB, off);
        denB += __shfl_down(denB, off);
    }
    if (lane == 0) {
        out[2 * b]     = numA / denA;
        out[2 * b + 1] = numB / denB;
    }
}

extern "C" void kernel_launch(void* const* d_in, const int* in_sizes, int n_in,
                              void* d_out, int out_size, void* d_ws, size_t ws_size,
                              hipStream_t stream) {
    const float* x    = (const float*)d_in[0];
    const float* W_ih = (const float*)d_in[1];
    const float* b_ih = (const float*)d_in[2];
    const float* W_hh = (const float*)d_in[3];
    const float* b_hh = (const float*)d_in[4];
    const float* fc_w = (const float*)d_in[5];
    const float* fc_b = (const float*)d_in[6];
    float* out = (float*)d_out;

    rnn_dual_kernel<<<BATCH / 2, 64, 0, stream>>>(x, W_ih, b_ih, W_hh, b_hh,
                                                  fc_w, fc_b, out);
}

// Round 7
// 1556.960 us; speedup vs baseline: 2.1968x; 2.1968x over previous
//
#include <hip/hip_runtime.h>
#include <math.h>

#define BATCH 128
#define SLEN  8000
#define HID   64
#define CHUNK 64                  // steps per fc flush; 8000 = 125 * 64
#define NCHUNK (SLEN / CHUNK)     // 125
#define ROWSTRIDE 68              // floats; row base = r*272 B, 16B-aligned

__device__ __forceinline__ float fast_exp2(float x) { return __builtin_amdgcn_exp2f(x); }
__device__ __forceinline__ float fast_rcp(float x)  { return __builtin_amdgcn_rcpf(x); }

__device__ __forceinline__ float bcast_lane(float v, int lane) {
    return __int_as_float(__builtin_amdgcn_readlane(__float_as_int(v), lane));
}

// tanh(x) = sign(x) * (e - 1)/(e + 1), e = 2^(2|x|*log2 e)   (UNCHANGED - bitwise)
__device__ __forceinline__ float tanh_fast(float x) {
    float ax = fabsf(x);
    float z  = fminf(ax * 2.8853900817779268f, 30.0f);
    float e  = fast_exp2(z);
    float r  = (e - 1.0f) * fast_rcp(e + 1.0f);
    return x < 0.0f ? -r : r;
}

__device__ __forceinline__ float sigmoid_fast(float x) {
    float z = fminf(fmaxf(-x * 1.4426950408889634f, -60.0f), 60.0f);
    float e = fast_exp2(z);
    return fast_rcp(1.0f + e);
}

// ALL-LDS broadcast + pk_fma. Solo-wave issue cadence is ~4 cyc/instr (fit of
// rounds 0-6), so the serial-path instruction count is the only lever:
//   R5 hybrid: 48-instr readlane section + 16 pk + 12 DS  ->  ~107 instrs, 540 cyc
//   here:      16 ds_read_b128 (full prev h row, broadcast) + 32 pk -> ~70 instrs
// Reads are issued at the top of the step so the LDS write->read turnaround
// hides under read-issue + seed + early pk consumption (compiler emits
// fine-grained lgkmcnt). Chain structure (a01=acc0/acc1, a23=acc2/acc3,
// ascending j) is identical -> bitwise-identical output.
#define PK_V(ACC, WPK, HPK)                                                 \
    asm volatile("v_pk_fma_f32 %0, %1, %2, %0"                              \
                 : "+v"(ACC) : "v"(WPK), "v"(HPK))

__global__ __launch_bounds__(64) void rnn_ldspk_kernel(
    const float* __restrict__ x,      // [B, S]
    const float* __restrict__ W_ih,   // [H, 1]
    const float* __restrict__ b_ih,   // [H]
    const float* __restrict__ W_hh,   // [H, H]
    const float* __restrict__ b_hh,   // [H]
    const float* __restrict__ fc_w,   // [2, H]
    const float* __restrict__ fc_b,   // [2]
    float* __restrict__ out)          // [B]
{
    __shared__ float hbuf[CHUNK * ROWSTRIDE];   // 64 rows of h history

    const int lane = threadIdx.x;               // == hidden index i
    const int b    = blockIdx.x;
    const float* xrow = x + (size_t)b * SLEN;

    // Lane i holds W_hh row i as float2 pairs:
    //   wpair[2q]   = (w[4q],   w[4q+1])  -> a01 chain   (q = 0..15)
    //   wpair[2q+1] = (w[4q+2], w[4q+3])  -> a23 chain
    float2 wpair[32];
    #pragma unroll
    for (int q = 0; q < 16; ++q) {
        float4 t = ((const float4*)(W_hh + lane * HID))[q];
        wpair[2*q]   = make_float2(t.x, t.y);
        wpair[2*q+1] = make_float2(t.z, t.w);
    }
    const float wih  = W_ih[lane];
    const float bias = b_ih[lane] + b_hh[lane];
    const float fcb0 = fc_b[0], fcb1 = fc_b[1];

    float h = 0.0f;                 // lane i holds h[i] (for the LDS write)
    float num = 0.0f, den = 0.0f;

    // h_{-1} = 0 lives in row 63 (read by step r=0 of chunk 0)
    hbuf[63 * ROWSTRIDE + lane] = 0.0f;

    float xv_next = xrow[lane];     // chunk 0's x values (one per lane)

    #pragma unroll 1
    for (int c = 0; c < NCHUNK; ++c) {
        float xcur = xv_next;
        // prefetch next chunk's x (off critical path; clamp index for last chunk)
        int nidx = (c + 1 < NCHUNK) ? (c + 1) * CHUNK + lane : lane;
        xv_next = xrow[nidx];

        #pragma unroll 4
        for (int r = 0; r < CHUNK; ++r) {
            // ---- issue ALL 16 broadcast reads of the previous h row FIRST ----
            // (same-address across lanes -> LDS broadcast, 0 conflicts;
            //  in-order DS pipe makes the RAW on last step's write safe)
            const float4* hp4 = (const float4*)(hbuf + ((r + 63) & 63) * ROWSTRIDE);
            float4 hr[16];
            #pragma unroll
            for (int q = 0; q < 16; ++q) hr[q] = hp4[q];

            float xv = bcast_lane(xcur, r);          // x_t

            // a01 = (acc0, acc1) chains, a23 = (acc2, acc3) chains — exact
            // same chain membership and in-chain order as the scalar version.
            float2 a01 = make_float2(fmaf(wih, xv, bias), 0.0f);
            float2 a23 = make_float2(0.0f, 0.0f);

            // ---- j = 0..63: 32 packed FMAs off the float4 halves ----
            #pragma unroll
            for (int q = 0; q < 16; ++q) {
                const float2* hp2 = (const float2*)&hr[q];   // register halves
                PK_V(a01, wpair[2*q],   hp2[0]);   // j = 4q, 4q+1
                PK_V(a23, wpair[2*q+1], hp2[1]);   // j = 4q+2, 4q+3
            }

            float a = (a01.x + a01.y) + (a23.x + a23.y);
            h = tanh_fast(a);
            hbuf[r * ROWSTRIDE + lane] = h;   // feeds step r+1 AND the fc head
        }
        __syncthreads();   // single wave -> lgkmcnt drain only

        // fc head for the chunk: lane processes row `lane` (1 timestep per lane)
        {
            const float4* rp = (const float4*)(hbuf + lane * ROWSTRIDE);
            float d0 = 0.f, d1 = 0.f;
            #pragma unroll
            for (int q = 0; q < 16; ++q) {
                float4 hv = rp[q];
                float4 f0 = ((const float4*)fc_w)[q];          // uniform -> s_load
                float4 f1 = ((const float4*)(fc_w + HID))[q];
                d0 += hv.x * f0.x + hv.y * f0.y + hv.z * f0.z + hv.w * f0.w;
                d1 += hv.x * f1.x + hv.y * f1.y + hv.z * f1.z + hv.w * f1.w;
            }
            float sel = sigmoid_fast(d0 + fcb0);
            float sco = sigmoid_fast(d1 + fcb1);
            num = fmaf(sco, sel, num);
            den += sel;
        }
        __syncthreads();   // hbuf reads done before next chunk overwrites
    }

    // Final cross-lane reduction of (num, den)
    #pragma unroll
    for (int off = 32; off > 0; off >>= 1) {
        num += __shfl_down(num, off);
        den += __shfl_down(den, off);
    }
    if (lane == 0) out[b] = num / den;
}

extern "C" void kernel_launch(void* const* d_in, const int* in_sizes, int n_in,
                              void* d_out, int out_size, void* d_ws, size_t ws_size,
                              hipStream_t stream) {
    const float* x    = (const float*)d_in[0];
    const float* W_ih = (const float*)d_in[1];
    const float* b_ih = (const float*)d_in[2];
    const float* W_hh = (const float*)d_in[3];
    const float* b_hh = (const float*)d_in[4];
    const float* fc_w = (const float*)d_in[5];
    const float* fc_b = (const float*)d_in[6];
    float* out = (float*)d_out;

    rnn_ldspk_kernel<<<BATCH, 64, 0, stream>>>(x, W_ih, b_ih, W_hh, b_hh,
                                               fc_w, fc_b, out);
}

// Round 8
// 1532.899 us; speedup vs baseline: 2.2313x; 1.0157x over previous
//
#include <hip/hip_runtime.h>
#include <math.h>
#include <stdint.h>

#define BATCH 128
#define SLEN  8000
#define HID   64
#define CHUNK 64                  // steps per fc flush; 8000 = 125 * 64
#define NCHUNK (SLEN / CHUNK)     // 125
#define ROWSTRIDE 68              // floats; row = 272 B, 16B-aligned
#define ROWBYTES  (ROWSTRIDE * 4) // 272

__device__ __forceinline__ float fast_exp2(float x) { return __builtin_amdgcn_exp2f(x); }
__device__ __forceinline__ float fast_rcp(float x)  { return __builtin_amdgcn_rcpf(x); }

__device__ __forceinline__ float bcast_lane(float v, int lane) {
    return __int_as_float(__builtin_amdgcn_readlane(__float_as_int(v), lane));
}

// tanh(x) = sign(x) * (e - 1)/(e + 1), e = 2^(2|x|*log2 e)   (UNCHANGED - bitwise)
__device__ __forceinline__ float tanh_fast(float x) {
    float ax = fabsf(x);
    float z  = fminf(ax * 2.8853900817779268f, 30.0f);
    float e  = fast_exp2(z);
    float r  = (e - 1.0f) * fast_rcp(e + 1.0f);
    return x < 0.0f ? -r : r;
}

__device__ __forceinline__ float sigmoid_fast(float x) {
    float z = fminf(fmaxf(-x * 1.4426950408889634f, -60.0f), 60.0f);
    float e = fast_exp2(z);
    return fast_rcp(1.0f + e);
}

// R7 left ~158 cyc/step of lgkm wait (VALUBusy accounting) — suspected coarse
// compiler s_waitcnt draining all 16 broadcast reads before the first pk.
// This version hand-counts the waits: issue 16 ds_read_b128, consume in 4
// groups gated by lgkmcnt(12/8/4/0) + sched_barrier(0) (rule: hipcc hoists
// reg-only VALU past asm lgkmcnt without the sched_barrier). Arithmetic is
// byte-identical to R7 -> bitwise-identical output.

#define RD(V, O) asm volatile("ds_read_b128 %0, %1 offset:" #O \
                              : "=v"(V) : "v"(rdaddr))

#define PKV(ACC, W2, H2) asm volatile("v_pk_fma_f32 %0, %1, %2, %0" \
                                      : "+v"(ACC) : "v"(W2), "v"(H2))

#define LO(V) (*(const float2*)&(V))
#define HI(V) (*((const float2*)&(V) + 1))

#define WAITSB(N) do {                                            \
    asm volatile("s_waitcnt lgkmcnt(" #N ")" ::: "memory");       \
    __builtin_amdgcn_sched_barrier(0);                            \
} while (0)

// One RNN step: reads prev h row at rdaddr (broadcast), writes h to wraddr.
// Wait math (in-order DS pipe): outstanding at WAITSB(12) = [prev write +]
// 16 reads; <=12 left  =>  write + reads q0..q3 retired — exactly what
// group 0 consumes. Groups 1-3 analogous at 8/4/0.
#define STEP(R_) do {                                                        \
    float4 t0,t1,t2,t3,t4,t5,t6,t7,t8,t9,tA,tB,tC,tD,tE,tF;                  \
    RD(t0, 0);   RD(t1, 16);  RD(t2, 32);  RD(t3, 48);                       \
    RD(t4, 64);  RD(t5, 80);  RD(t6, 96);  RD(t7, 112);                      \
    RD(t8, 128); RD(t9, 144); RD(tA, 160); RD(tB, 176);                      \
    RD(tC, 192); RD(tD, 208); RD(tE, 224); RD(tF, 240);                      \
    float xv = bcast_lane(xcur, R_);                                         \
    float2 a01 = make_float2(fmaf(wih, xv, bias), 0.0f);                     \
    float2 a23 = make_float2(0.0f, 0.0f);                                    \
    WAITSB(12);                                                              \
    PKV(a01, wpair[0], LO(t0));  PKV(a23, wpair[1],  HI(t0));                \
    PKV(a01, wpair[2], LO(t1));  PKV(a23, wpair[3],  HI(t1));                \
    PKV(a01, wpair[4], LO(t2));  PKV(a23, wpair[5],  HI(t2));                \
    PKV(a01, wpair[6], LO(t3));  PKV(a23, wpair[7],  HI(t3));                \
    WAITSB(8);                                                               \
    PKV(a01, wpair[8],  LO(t4)); PKV(a23, wpair[9],  HI(t4));                \
    PKV(a01, wpair[10], LO(t5)); PKV(a23, wpair[11], HI(t5));                \
    PKV(a01, wpair[12], LO(t6)); PKV(a23, wpair[13], HI(t6));                \
    PKV(a01, wpair[14], LO(t7)); PKV(a23, wpair[15], HI(t7));                \
    WAITSB(4);                                                               \
    PKV(a01, wpair[16], LO(t8)); PKV(a23, wpair[17], HI(t8));                \
    PKV(a01, wpair[18], LO(t9)); PKV(a23, wpair[19], HI(t9));                \
    PKV(a01, wpair[20], LO(tA)); PKV(a23, wpair[21], HI(tA));                \
    PKV(a01, wpair[22], LO(tB)); PKV(a23, wpair[23], HI(tB));                \
    WAITSB(0);                                                               \
    PKV(a01, wpair[24], LO(tC)); PKV(a23, wpair[25], HI(tC));                \
    PKV(a01, wpair[26], LO(tD)); PKV(a23, wpair[27], HI(tD));                \
    PKV(a01, wpair[28], LO(tE)); PKV(a23, wpair[29], HI(tE));                \
    PKV(a01, wpair[30], LO(tF)); PKV(a23, wpair[31], HI(tF));                \
    float aa = (a01.x + a01.y) + (a23.x + a23.y);                            \
    float hnew = tanh_fast(aa);                                              \
    asm volatile("ds_write_b32 %0, %1" :: "v"(wraddr), "v"(hnew) : "memory");\
} while (0)

__global__ __launch_bounds__(64) void rnn_asmwait_kernel(
    const float* __restrict__ x,      // [B, S]
    const float* __restrict__ W_ih,   // [H, 1]
    const float* __restrict__ b_ih,   // [H]
    const float* __restrict__ W_hh,   // [H, H]
    const float* __restrict__ b_hh,   // [H]
    const float* __restrict__ fc_w,   // [2, H]
    const float* __restrict__ fc_b,   // [2]
    float* __restrict__ out)          // [B]
{
    __shared__ float hbuf[CHUNK * ROWSTRIDE];   // 64 rows of h history

    const int lane = threadIdx.x;               // == hidden index i
    const int b    = blockIdx.x;
    const float* xrow = x + (size_t)b * SLEN;

    // Lane i holds W_hh row i as float2 pairs:
    //   wpair[2q]   = (w[4q],   w[4q+1])  -> a01 chain   (q = 0..15)
    //   wpair[2q+1] = (w[4q+2], w[4q+3])  -> a23 chain
    float2 wpair[32];
    #pragma unroll
    for (int q = 0; q < 16; ++q) {
        float4 t = ((const float4*)(W_hh + lane * HID))[q];
        wpair[2*q]   = make_float2(t.x, t.y);
        wpair[2*q+1] = make_float2(t.z, t.w);
    }
    const float wih  = W_ih[lane];
    const float bias = b_ih[lane] + b_hh[lane];
    const float fcb0 = fc_b[0], fcb1 = fc_b[1];

    float num = 0.0f, den = 0.0f;

    // LDS byte addresses (gfx9 flat-LDS aperture lives in the high 32 bits,
    // so the low 32 bits of a generic LDS pointer are the LDS byte offset).
    const uint32_t hb    = (uint32_t)(uintptr_t)&hbuf[0];
    const uint32_t lane4 = (uint32_t)(lane * 4);

    // h_{-1} = 0 -> row 63, written via asm so it's ordered with asm reads
    {
        float z0 = 0.0f;
        uint32_t ia = hb + 63 * ROWBYTES + lane4;
        asm volatile("ds_write_b32 %0, %1" :: "v"(ia), "v"(z0) : "memory");
    }

    float xv_next = xrow[lane];     // chunk 0's x values (one per lane)

    #pragma unroll 1
    for (int c = 0; c < NCHUNK; ++c) {
        float xcur = xv_next;
        // prefetch next chunk's x (off critical path; clamp index for last chunk)
        int nidx = (c + 1 < NCHUNK) ? (c + 1) * CHUNK + lane : lane;
        xv_next = xrow[nidx];

        uint32_t rdaddr = hb + 63 * ROWBYTES;   // step 0 reads row 63
        uint32_t wraddr = hb + lane4;           // step 0 writes row 0

        #pragma unroll 4
        for (int r = 0; r < CHUNK; ++r) {
            STEP(r);
            rdaddr = wraddr - lane4;            // next step reads row r
            wraddr += ROWBYTES;
        }
        __syncthreads();   // drains lgkm (incl. last write); hbuf complete

        // fc head for the chunk: lane processes row `lane` (1 timestep per lane)
        {
            const float4* rp = (const float4*)(hbuf + lane * ROWSTRIDE);
            float d0 = 0.f, d1 = 0.f;
            #pragma unroll
            for (int q = 0; q < 16; ++q) {
                float4 hv = rp[q];
                float4 f0 = ((const float4*)fc_w)[q];          // uniform -> s_load
                float4 f1 = ((const float4*)(fc_w + HID))[q];
                d0 += hv.x * f0.x + hv.y * f0.y + hv.z * f0.z + hv.w * f0.w;
                d1 += hv.x * f1.x + hv.y * f1.y + hv.z * f1.z + hv.w * f1.w;
            }
            float sel = sigmoid_fast(d0 + fcb0);
            float sco = sigmoid_fast(d1 + fcb1);
            num = fmaf(sco, sel, num);
            den += sel;
        }
        __syncthreads();   // hbuf reads done before next chunk overwrites
    }

    // Final cross-lane reduction of (num, den)
    #pragma unroll
    for (int off = 32; off > 0; off >>= 1) {
        num += __shfl_down(num, off);
        den += __shfl_down(den, off);
    }
    if (lane == 0) out[b] = num / den;
}

extern "C" void kernel_launch(void* const* d_in, const int* in_sizes, int n_in,
                              void* d_out, int out_size, void* d_ws, size_t ws_size,
                              hipStream_t stream) {
    const float* x    = (const float*)d_in[0];
    const float* W_ih = (const float*)d_in[1];
    const float* b_ih = (const float*)d_in[2];
    const float* W_hh = (const float*)d_in[3];
    const float* b_hh = (const float*)d_in[4];
    const float* fc_w = (const float*)d_in[5];
    const float* fc_b = (const float*)d_in[6];
    float* out = (float*)d_out;

    rnn_asmwait_kernel<<<BATCH, 64, 0, stream>>>(x, W_ih, b_ih, W_hh, b_hh,
                                                 fc_w, fc_b, out);
}